// Round 15
// baseline (392.649 us; speedup 1.0000x reference)
//
#include <hip/hip_runtime.h>
#include <hip/hip_fp16.h>

#define NN 32      // nodes
#define FF 64      // GAT out features
#define HH 128     // LSTM hidden
#define G4 512     // 4*H
#define BB 32      // batch
#define TT 512     // time steps
#define ET 128     // 96 edges + 32 self loops
#define NPOS (BB*TT)
#define POSB 32    // positions per gatxw block

__device__ __forceinline__ float frcp(float x) { return __builtin_amdgcn_rcpf(x); }

// ---------------- prep: fold GAT linear + MFMA B-fragment transpose (R27: 256-thread scan) ----
// lstm thread tid = w*64 + l (wave w 0..3, lane l 0..63). Wave w owns units w*32..+31 as
// TWO 16-col tiles (tt=0,1) x 4 gates. Wt16[tid*256 + ((tt*4+g)*4+q)*8 + e] =
//   f16(W_hh[(q*32 + (l>>4)*8 + e)][g*128 + w*32 + tt*16 + (l&15)])
__global__ __launch_bounds__(512) void prep_kernel(const float* __restrict__ w_gat,
                                                   const float* __restrict__ b_gat,
                                                   const float* __restrict__ W_ih,
                                                   const float* __restrict__ W_hh,
                                                   float* __restrict__ W_eff,
                                                   float* __restrict__ biasp,
                                                   float* __restrict__ Wt) {
  int j = threadIdx.x;
  int n = blockIdx.x;
  float accw = 0.f, accb = 0.f;
#pragma unroll 8
  for (int f = 0; f < FF; ++f) {
    float wv = W_ih[(n * FF + f) * G4 + j];
    accw = fmaf(w_gat[f], wv, accw);
    accb = fmaf(b_gat[f], wv, accb);
  }
  W_eff[n * G4 + j] = accw;
  biasp[n * G4 + j] = accb;
  __half* Wt16 = (__half*)Wt;
  int g0 = (n * G4 + j) * 4;
#pragma unroll
  for (int qq = 0; qq < 4; ++qq) {
    int E = g0 + qq;
    int tl = E >> 8;             // lstm thread 0..255
    int idx = E & 255;
    int ft = idx >> 3;           // frag 0..31
    int e = idx & 7;
    int tt = ft >> 4, g = (ft >> 2) & 3, q = ft & 3;
    int w = tl >> 6, l = tl & 63;
    int k = q * 32 + ((l >> 4) * 8) + e;
    int col = g * 128 + w * 32 + tt * 16 + (l & 15);
    Wt16[E] = __float2half(W_hh[k * G4 + col]);
  }
}

// ---------------- fused GAT + xw: 32 positions per block (R25-verified, f32 xw) ----------------
__global__ __launch_bounds__(256) void gatxw_kernel(const float* __restrict__ x_seq,
                                                    const int* __restrict__ ei,
                                                    const float* __restrict__ w_gat,
                                                    const float* __restrict__ att_src,
                                                    const float* __restrict__ att_dst,
                                                    const float* __restrict__ b_ih,
                                                    const float* __restrict__ b_hh,
                                                    const float* __restrict__ W_eff,
                                                    const float* __restrict__ biasp,
                                                    float* __restrict__ xw) {
  __shared__ int srt[ET];
  __shared__ int offs[NN + 1];
  __shared__ int cnt[NN];
  __shared__ float xs[POSB * NN];   // 1024
  __shared__ float sl[POSB * NN];   // 1024
  __shared__ float scal_sh[2];
  int tid = threadIdx.x;
  int posbase = blockIdx.x * POSB;
  float we0[NN], we1[NN];
#pragma unroll
  for (int nn = 0; nn < NN; ++nn) {
    we0[nn] = W_eff[nn * G4 + tid];
    we1[nn] = W_eff[nn * G4 + 256 + tid];
  }
  float b0 = b_ih[tid] + b_hh[tid];
  float b1 = b_ih[256 + tid] + b_hh[256 + tid];
#pragma unroll 8
  for (int n = 0; n < NN; ++n) {
    b0 += biasp[n * G4 + tid];
    b1 += biasp[n * G4 + 256 + tid];
  }
  if (tid < NN) cnt[tid] = 0;
  __syncthreads();
  int es = 0, ed = 0, tk = 0;
  if (tid < ET) {
    if (tid < 96) { es = ei[tid]; ed = ei[96 + tid]; }
    else { es = tid - 96; ed = tid - 96; }
    tk = atomicAdd(&cnt[ed], 1);
  }
  __syncthreads();
  if (tid == 0) {
    offs[0] = 0;
    for (int n = 0; n < NN; ++n) offs[n + 1] = offs[n] + cnt[n];
  }
  if (tid == 1) {
    float cs = 0.f, cd = 0.f;
    for (int f = 0; f < FF; ++f) {
      cs = fmaf(w_gat[f], att_src[f], cs);
      cd = fmaf(w_gat[f], att_dst[f], cd);
    }
    scal_sh[0] = cs;
    scal_sh[1] = cd;
  }
  __syncthreads();
  if (tid < ET) srt[offs[ed] + tk] = es;
#pragma unroll
  for (int c = 0; c < POSB * NN / 256; ++c)
    xs[c * 256 + tid] = x_seq[posbase * NN + c * 256 + tid];  // coalesced
  __syncthreads();
  float cs = scal_sh[0], cd = scal_sh[1];
  int n = tid & 31;
  int e0 = offs[n], e1 = offs[n + 1];
#pragma unroll
  for (int pb = 0; pb < POSB / 8; ++pb) {
    int p = pb * 8 + (tid >> 5);
    int base = p * 32;
    float xn = xs[base + n];
    float cdxn = cd * xn;
    float m = -3.0e38f;
    for (int e = e0; e < e1; ++e) {
      float ev = fmaf(cs, xs[base + srt[e]], cdxn);
      ev = ev > 0.f ? ev : 0.2f * ev;  // LeakyReLU(0.2)
      m = fmaxf(m, ev);
    }
    float z = 0.f, sa = 0.f;
    for (int e = e0; e < e1; ++e) {
      float xsv = xs[base + srt[e]];
      float ev = fmaf(cs, xsv, cdxn);
      ev = ev > 0.f ? ev : 0.2f * ev;
      float ex = __expf(ev - m);
      z += ex;
      sa = fmaf(ex, xsv, sa);
    }
    sl[base + n] = sa * frcp(z);
  }
  __syncthreads();
#pragma unroll 4
  for (int pp = 0; pp < POSB; ++pp) {
    const float4* sp = (const float4*)&sl[pp * 32];
    float a0 = b0, a1 = b1;
#pragma unroll
    for (int q = 0; q < 8; ++q) {
      float4 sv = sp[q];
      a0 = fmaf(sv.x, we0[4 * q], a0);
      a0 = fmaf(sv.y, we0[4 * q + 1], a0);
      a0 = fmaf(sv.z, we0[4 * q + 2], a0);
      a0 = fmaf(sv.w, we0[4 * q + 3], a0);
      a1 = fmaf(sv.x, we1[4 * q], a1);
      a1 = fmaf(sv.y, we1[4 * q + 1], a1);
      a1 = fmaf(sv.z, we1[4 * q + 2], a1);
      a1 = fmaf(sv.w, we1[4 * q + 3], a1);
    }
    size_t row = (size_t)(posbase + pp) * G4;
    xw[row + tid] = a0;
    xw[row + 256 + tid] = a1;
  }
}

// ---------------- LSTM scan: R27 — 4 waves (1/SIMD), 32 units/wave, MFMA ----------------
// R25 (8 waves = 2/SIMD) had both barrier-locked waves at the same phase: no latency
// hiding, only 2x issue contention on every serial-chain component. R27: 4 waves, solo
// issue per SIMD. Wave w owns units w*32..+31 (2 col-tiles x 4 gates = 8 acc quads,
// 32 MFMAs/step, B frags v64-191). Dual act chains interleave (hides trans latency).
// R26 lesson: keep f32 xw via HBM (prefetch-hidden, free); no sl-MFMA in the chain.
//
// Regs: v32-47 A h-frags | v48 xaddr v49/50 rdA/B v51/52 wrA/B v53/54 c0/c1
// v55 -log2e v56 2log2e | v64-191 B frags | v192-223 acc (8 quads) |
// v224-239 x ring (2 phases x 8) | v240-251 act temps

#define MQ8(AQ, B0, B1, B2, B3, B4, B5, B6, B7) \
  "v_mfma_f32_16x16x32_f16 v[192:195], v[" AQ "], v[" B0 "], v[192:195]\n\t" \
  "v_mfma_f32_16x16x32_f16 v[196:199], v[" AQ "], v[" B1 "], v[196:199]\n\t" \
  "v_mfma_f32_16x16x32_f16 v[200:203], v[" AQ "], v[" B2 "], v[200:203]\n\t" \
  "v_mfma_f32_16x16x32_f16 v[204:207], v[" AQ "], v[" B3 "], v[204:207]\n\t" \
  "v_mfma_f32_16x16x32_f16 v[208:211], v[" AQ "], v[" B4 "], v[208:211]\n\t" \
  "v_mfma_f32_16x16x32_f16 v[212:215], v[" AQ "], v[" B5 "], v[212:215]\n\t" \
  "v_mfma_f32_16x16x32_f16 v[216:219], v[" AQ "], v[" B6 "], v[216:219]\n\t" \
  "v_mfma_f32_16x16x32_f16 v[220:223], v[" AQ "], v[" B7 "], v[220:223]\n\t"

#define PHASE(X0, X1, X2, X3, X4, X5, X6, X7, RD, WR) \
  "s_waitcnt vmcnt(8)\n\t" \
  "v_mov_b32 v192, " X0 "\n\t" \
  "v_mov_b32 v196, " X1 "\n\t" \
  "v_mov_b32 v200, " X2 "\n\t" \
  "v_mov_b32 v204, " X3 "\n\t" \
  "v_mov_b32 v208, " X4 "\n\t" \
  "v_mov_b32 v212, " X5 "\n\t" \
  "v_mov_b32 v216, " X6 "\n\t" \
  "v_mov_b32 v220, " X7 "\n\t" \
  "ds_read_b128 v[32:35], " RD "\n\t" \
  "ds_read_b128 v[36:39], " RD " offset:64\n\t" \
  "ds_read_b128 v[40:43], " RD " offset:128\n\t" \
  "ds_read_b128 v[44:47], " RD " offset:192\n\t" \
  "s_waitcnt lgkmcnt(3)\n\t" \
  MQ8("32:35", "64:67",  "80:83",  "96:99",   "112:115", "128:131", "144:147", "160:163", "176:179") \
  "s_waitcnt lgkmcnt(2)\n\t" \
  MQ8("36:39", "68:71",  "84:87",  "100:103", "116:119", "132:135", "148:151", "164:167", "180:183") \
  "s_waitcnt lgkmcnt(1)\n\t" \
  MQ8("40:43", "72:75",  "88:91",  "104:107", "120:123", "136:139", "152:155", "168:171", "184:187") \
  "s_waitcnt lgkmcnt(0)\n\t" \
  MQ8("44:47", "76:79",  "92:95",  "108:111", "124:127", "140:143", "156:159", "172:175", "188:191") \
  "global_load_dword " X0 ", v48, %[xwb]\n\t" \
  "global_load_dword " X1 ", v48, %[xwb] offset:512\n\t" \
  "global_load_dword " X2 ", v48, %[xwb] offset:1024\n\t" \
  "global_load_dword " X3 ", v48, %[xwb] offset:1536\n\t" \
  "global_load_dword " X4 ", v48, %[xwb] offset:64\n\t" \
  "global_load_dword " X5 ", v48, %[xwb] offset:576\n\t" \
  "global_load_dword " X6 ", v48, %[xwb] offset:1088\n\t" \
  "global_load_dword " X7 ", v48, %[xwb] offset:1600\n\t" \
  "v_add_u32 v48, 0x800, v48\n\t" \
  "s_nop 7\n\t" \
  "s_nop 7\n\t" \
  "v_mul_f32 v240, v55, v192\n\t" \
  "v_mul_f32 v241, v55, v196\n\t" \
  "v_mul_f32 v242, v56, v200\n\t" \
  "v_mul_f32 v243, v55, v204\n\t" \
  "v_mul_f32 v244, v55, v208\n\t" \
  "v_mul_f32 v245, v55, v212\n\t" \
  "v_mul_f32 v246, v56, v216\n\t" \
  "v_mul_f32 v247, v55, v220\n\t" \
  "v_exp_f32 v240, v240\n\t" \
  "v_exp_f32 v241, v241\n\t" \
  "v_exp_f32 v242, v242\n\t" \
  "v_exp_f32 v243, v243\n\t" \
  "v_exp_f32 v244, v244\n\t" \
  "v_exp_f32 v245, v245\n\t" \
  "v_exp_f32 v246, v246\n\t" \
  "v_exp_f32 v247, v247\n\t" \
  "v_add_f32 v240, 1.0, v240\n\t" \
  "v_add_f32 v241, 1.0, v241\n\t" \
  "v_add_f32 v242, 1.0, v242\n\t" \
  "v_add_f32 v243, 1.0, v243\n\t" \
  "v_add_f32 v244, 1.0, v244\n\t" \
  "v_add_f32 v245, 1.0, v245\n\t" \
  "v_add_f32 v246, 1.0, v246\n\t" \
  "v_add_f32 v247, 1.0, v247\n\t" \
  "v_rcp_f32 v240, v240\n\t" \
  "v_rcp_f32 v241, v241\n\t" \
  "v_rcp_f32 v242, v242\n\t" \
  "v_rcp_f32 v243, v243\n\t" \
  "v_rcp_f32 v244, v244\n\t" \
  "v_rcp_f32 v245, v245\n\t" \
  "v_rcp_f32 v246, v246\n\t" \
  "v_rcp_f32 v247, v247\n\t" \
  "v_fma_f32 v242, -2.0, v242, 1.0\n\t" \
  "v_fma_f32 v246, -2.0, v246, 1.0\n\t" \
  "v_mul_f32 v248, v240, v242\n\t" \
  "v_mul_f32 v249, v244, v246\n\t" \
  "v_fma_f32 v53, v241, v53, v248\n\t" \
  "v_fma_f32 v54, v245, v54, v249\n\t" \
  "v_mul_f32 v250, v56, v53\n\t" \
  "v_mul_f32 v251, v56, v54\n\t" \
  "v_exp_f32 v250, v250\n\t" \
  "v_exp_f32 v251, v251\n\t" \
  "v_add_f32 v250, 1.0, v250\n\t" \
  "v_add_f32 v251, 1.0, v251\n\t" \
  "v_rcp_f32 v250, v250\n\t" \
  "v_rcp_f32 v251, v251\n\t" \
  "v_fma_f32 v250, -2.0, v250, 1.0\n\t" \
  "v_fma_f32 v251, -2.0, v251, 1.0\n\t" \
  "v_mul_f32 v250, v243, v250\n\t" \
  "v_mul_f32 v251, v247, v251\n\t" \
  "v_cvt_f16_f32 v250, v250\n\t" \
  "v_cvt_f16_f32 v251, v251\n\t" \
  "ds_write_b16 " WR ", v250\n\t" \
  "ds_write_b16 " WR ", v251 offset:32\n\t" \
  "s_waitcnt lgkmcnt(0)\n\t" \
  "s_barrier\n\t"

__global__ __launch_bounds__(256, 1) void lstm_kernel(const float* __restrict__ xw,
                                                      const float* __restrict__ Wt,
                                                      const float* __restrict__ W_fc,
                                                      const float* __restrict__ b_fc,
                                                      float* __restrict__ out) {
  __shared__ __align__(16) float hlds[128];  // f16 h: bufA bytes [0,256), bufB [256,512)
  int b = blockIdx.x, tid = threadIdx.x;
  int w = tid >> 6, l = tid & 63;
  int u0 = w * 32 + (l & 15);                // first unit (tile tt=0); tt=1 is u0+16
  if (tid < 128) hlds[tid] = 0.f;
  const float* xwb = xw + (size_t)b * TT * G4;
  unsigned xoff0 = (unsigned)(u0 * 4);       // gate/tile offsets via imm (g*512 + tt*64)
  unsigned wtoff = (unsigned)(tid * 512);    // 256 f16 = 512 B per thread
  unsigned lbase = (unsigned)(uintptr_t)&hlds[0];  // LDS aperture is 4GB-aligned
  unsigned rda = lbase + (unsigned)((l >> 4) * 16);  // A-frag k-chunk base
  unsigned rdb = rda + 256;
  unsigned wra = lbase + (unsigned)(u0 * 2); // f16 elem; 4-way same-addr write; u1 at +32B
  unsigned wrb = wra + 256;
  __syncthreads();
  asm volatile(
    "v_mov_b32 v48, %[xo]\n\t"
    "v_mov_b32 v49, %[rda]\n\t"
    "v_mov_b32 v50, %[rdb]\n\t"
    "v_mov_b32 v51, %[wra]\n\t"
    "v_mov_b32 v52, %[wrb]\n\t"
    "v_mov_b32 v53, 0\n\t"                    // c0
    "v_mov_b32 v54, 0\n\t"                    // c1
    "v_mov_b32 v55, 0xbfb8aa3b\n\t"           // -log2e
    "v_mov_b32 v56, 0x4038aa3b\n\t"           // 2*log2e
    // zero acc regs 1-3 of all 8 quads (never read; bounded growth)
    "v_mov_b32 v193, 0\n\t" "v_mov_b32 v194, 0\n\t" "v_mov_b32 v195, 0\n\t"
    "v_mov_b32 v197, 0\n\t" "v_mov_b32 v198, 0\n\t" "v_mov_b32 v199, 0\n\t"
    "v_mov_b32 v201, 0\n\t" "v_mov_b32 v202, 0\n\t" "v_mov_b32 v203, 0\n\t"
    "v_mov_b32 v205, 0\n\t" "v_mov_b32 v206, 0\n\t" "v_mov_b32 v207, 0\n\t"
    "v_mov_b32 v209, 0\n\t" "v_mov_b32 v210, 0\n\t" "v_mov_b32 v211, 0\n\t"
    "v_mov_b32 v213, 0\n\t" "v_mov_b32 v214, 0\n\t" "v_mov_b32 v215, 0\n\t"
    "v_mov_b32 v217, 0\n\t" "v_mov_b32 v218, 0\n\t" "v_mov_b32 v219, 0\n\t"
    "v_mov_b32 v221, 0\n\t" "v_mov_b32 v222, 0\n\t" "v_mov_b32 v223, 0\n\t"
    // x ring: t=0 -> v224-231, t=1 -> v232-239 (8 dwords: 2 tiles x 4 gates)
    "global_load_dword v224, v48, %[xwb]\n\t"
    "global_load_dword v225, v48, %[xwb] offset:512\n\t"
    "global_load_dword v226, v48, %[xwb] offset:1024\n\t"
    "global_load_dword v227, v48, %[xwb] offset:1536\n\t"
    "global_load_dword v228, v48, %[xwb] offset:64\n\t"
    "global_load_dword v229, v48, %[xwb] offset:576\n\t"
    "global_load_dword v230, v48, %[xwb] offset:1088\n\t"
    "global_load_dword v231, v48, %[xwb] offset:1600\n\t"
    "v_add_u32 v48, 0x800, v48\n\t"
    "global_load_dword v232, v48, %[xwb]\n\t"
    "global_load_dword v233, v48, %[xwb] offset:512\n\t"
    "global_load_dword v234, v48, %[xwb] offset:1024\n\t"
    "global_load_dword v235, v48, %[xwb] offset:1536\n\t"
    "global_load_dword v236, v48, %[xwb] offset:64\n\t"
    "global_load_dword v237, v48, %[xwb] offset:576\n\t"
    "global_load_dword v238, v48, %[xwb] offset:1088\n\t"
    "global_load_dword v239, v48, %[xwb] offset:1600\n\t"
    "v_add_u32 v48, 0x800, v48\n\t"
    // 256 f16 B-frag weights -> v64..v191 (32 x dwordx4)
    "global_load_dwordx4 v[64:67], %[wto], %[wtb] offset:0\n\t"
    "global_load_dwordx4 v[68:71], %[wto], %[wtb] offset:16\n\t"
    "global_load_dwordx4 v[72:75], %[wto], %[wtb] offset:32\n\t"
    "global_load_dwordx4 v[76:79], %[wto], %[wtb] offset:48\n\t"
    "global_load_dwordx4 v[80:83], %[wto], %[wtb] offset:64\n\t"
    "global_load_dwordx4 v[84:87], %[wto], %[wtb] offset:80\n\t"
    "global_load_dwordx4 v[88:91], %[wto], %[wtb] offset:96\n\t"
    "global_load_dwordx4 v[92:95], %[wto], %[wtb] offset:112\n\t"
    "global_load_dwordx4 v[96:99], %[wto], %[wtb] offset:128\n\t"
    "global_load_dwordx4 v[100:103], %[wto], %[wtb] offset:144\n\t"
    "global_load_dwordx4 v[104:107], %[wto], %[wtb] offset:160\n\t"
    "global_load_dwordx4 v[108:111], %[wto], %[wtb] offset:176\n\t"
    "global_load_dwordx4 v[112:115], %[wto], %[wtb] offset:192\n\t"
    "global_load_dwordx4 v[116:119], %[wto], %[wtb] offset:208\n\t"
    "global_load_dwordx4 v[120:123], %[wto], %[wtb] offset:224\n\t"
    "global_load_dwordx4 v[124:127], %[wto], %[wtb] offset:240\n\t"
    "global_load_dwordx4 v[128:131], %[wto], %[wtb] offset:256\n\t"
    "global_load_dwordx4 v[132:135], %[wto], %[wtb] offset:272\n\t"
    "global_load_dwordx4 v[136:139], %[wto], %[wtb] offset:288\n\t"
    "global_load_dwordx4 v[140:143], %[wto], %[wtb] offset:304\n\t"
    "global_load_dwordx4 v[144:147], %[wto], %[wtb] offset:320\n\t"
    "global_load_dwordx4 v[148:151], %[wto], %[wtb] offset:336\n\t"
    "global_load_dwordx4 v[152:155], %[wto], %[wtb] offset:352\n\t"
    "global_load_dwordx4 v[156:159], %[wto], %[wtb] offset:368\n\t"
    "global_load_dwordx4 v[160:163], %[wto], %[wtb] offset:384\n\t"
    "global_load_dwordx4 v[164:167], %[wto], %[wtb] offset:400\n\t"
    "global_load_dwordx4 v[168:171], %[wto], %[wtb] offset:416\n\t"
    "global_load_dwordx4 v[172:175], %[wto], %[wtb] offset:432\n\t"
    "global_load_dwordx4 v[176:179], %[wto], %[wtb] offset:448\n\t"
    "global_load_dwordx4 v[180:183], %[wto], %[wtb] offset:464\n\t"
    "global_load_dwordx4 v[184:187], %[wto], %[wtb] offset:480\n\t"
    "global_load_dwordx4 v[188:191], %[wto], %[wtb] offset:496\n\t"
    "s_waitcnt vmcnt(0)\n\t"
    "s_movk_i32 s20, 0x100\n\t"    // 256 iterations x 2 phases = 512 steps
    "L_lstm_%=:\n\t"
    PHASE("v224", "v225", "v226", "v227", "v228", "v229", "v230", "v231", "v49", "v52")
    PHASE("v232", "v233", "v234", "v235", "v236", "v237", "v238", "v239", "v50", "v51")
    "s_sub_u32 s20, s20, 1\n\t"
    "s_cmp_lg_u32 s20, 0\n\t"
    "s_cbranch_scc1 L_lstm_%=\n\t"
    "s_waitcnt vmcnt(0) lgkmcnt(0)\n\t"
    :
    : [xwb]"s"(xwb), [wtb]"s"(Wt), [wto]"v"(wtoff), [xo]"v"(xoff0),
      [rda]"v"(rda), [rdb]"v"(rdb), [wra]"v"(wra), [wrb]"v"(wrb)
    : "memory", "scc", "s20",
      "v32","v33","v34","v35","v36","v37","v38","v39",
      "v40","v41","v42","v43","v44","v45","v46","v47",
      "v48","v49","v50","v51","v52","v53","v54","v55","v56",
      "v64","v65","v66","v67","v68","v69","v70","v71",
      "v72","v73","v74","v75","v76","v77","v78","v79",
      "v80","v81","v82","v83","v84","v85","v86","v87",
      "v88","v89","v90","v91","v92","v93","v94","v95",
      "v96","v97","v98","v99","v100","v101","v102","v103",
      "v104","v105","v106","v107","v108","v109","v110","v111",
      "v112","v113","v114","v115","v116","v117","v118","v119",
      "v120","v121","v122","v123","v124","v125","v126","v127",
      "v128","v129","v130","v131","v132","v133","v134","v135",
      "v136","v137","v138","v139","v140","v141","v142","v143",
      "v144","v145","v146","v147","v148","v149","v150","v151",
      "v152","v153","v154","v155","v156","v157","v158","v159",
      "v160","v161","v162","v163","v164","v165","v166","v167",
      "v168","v169","v170","v171","v172","v173","v174","v175",
      "v176","v177","v178","v179","v180","v181","v182","v183",
      "v184","v185","v186","v187","v188","v189","v190","v191",
      "v192","v193","v194","v195","v196","v197","v198","v199",
      "v200","v201","v202","v203","v204","v205","v206","v207",
      "v208","v209","v210","v211","v212","v213","v214","v215",
      "v216","v217","v218","v219","v220","v221","v222","v223",
      "v224","v225","v226","v227","v228","v229","v230","v231",
      "v232","v233","v234","v235","v236","v237","v238","v239",
      "v240","v241","v242","v243","v244","v245","v246","v247",
      "v248","v249","v250","v251");
  __syncthreads();
  // final h (after t=511, odd -> buffer A): f16 linear hlds bytes [0,256)
  if (tid < 4) {
    const __half* hf = (const __half*)hlds;
    float acc = b_fc[tid];
#pragma unroll 8
    for (int k = 0; k < HH; ++k)
      acc = fmaf(__half2float(hf[k]), W_fc[k * 4 + tid], acc);
    out[b * 4 + tid] = acc;
  }
}

extern "C" void kernel_launch(void* const* d_in, const int* in_sizes, int n_in,
                              void* d_out, int out_size, void* d_ws, size_t ws_size,
                              hipStream_t stream) {
  const float* x_seq   = (const float*)d_in[0];
  const int*   ei      = (const int*)d_in[1];
  const float* w_gat   = (const float*)d_in[2];
  const float* att_src = (const float*)d_in[3];
  const float* att_dst = (const float*)d_in[4];
  const float* b_gat   = (const float*)d_in[5];
  const float* W_ih    = (const float*)d_in[6];
  const float* W_hh    = (const float*)d_in[7];
  const float* b_ih    = (const float*)d_in[8];
  const float* b_hh    = (const float*)d_in[9];
  const float* W_fc    = (const float*)d_in[10];
  const float* b_fc    = (const float*)d_in[11];

  float* ws = (float*)d_ws;
  float* Wt    = ws;                            // 65536 f16 used (region reserved as 65536 f32)
  float* xw    = Wt + 65536;                    // (16384+8)*512 f (pad rows: 2-deep prefetch)
  float* W_eff = xw + (size_t)(NPOS + 8) * G4;  // 32*512
  float* biasp = W_eff + NN * G4;               // 32*512

  prep_kernel<<<NN, G4, 0, stream>>>(w_gat, b_gat, W_ih, W_hh, W_eff, biasp, Wt);
  gatxw_kernel<<<NPOS / POSB, 256, 0, stream>>>(x_seq, ei, w_gat, att_src, att_dst,
                                                b_ih, b_hh, W_eff, biasp, xw);
  lstm_kernel<<<BB, 256, 0, stream>>>(xw, Wt, W_fc, b_fc, (float*)d_out);
}

// Round 16
// 335.529 us; speedup vs baseline: 1.1702x; 1.1702x over previous
//
#include <hip/hip_runtime.h>
#include <hip/hip_fp16.h>

#define NN 32      // nodes
#define FF 64      // GAT out features
#define HH 128     // LSTM hidden
#define G4 512     // 4*H
#define BB 32      // batch
#define TT 512     // time steps
#define ET 128     // 96 edges + 32 self loops
#define NPOS (BB*TT)
#define POSB 32    // positions per gatxw block

__device__ __forceinline__ float frcp(float x) { return __builtin_amdgcn_rcpf(x); }

// ---------------- prep: fold GAT linear + MFMA B-fragment weight transpose ----------------
// R25 layout: lstm thread tid = w*64 + l (wave w 0..7, lane l 0..63). Wave w owns hidden
// units w*16..+15, all 4 gates as 16-col MFMA B tiles. B frag (g,q): lane l holds
// B[k=(l>>4)*8+e][col=l&15] of K-tile q, e=0..7 packed 2/VGPR.
// Wt16[tid*128 + (g*4+q)*8 + e] = f16(W_hh[(q*32 + (l>>4)*8 + e)][g*128 + w*16 + (l&15)])
__global__ __launch_bounds__(512) void prep_kernel(const float* __restrict__ w_gat,
                                                   const float* __restrict__ b_gat,
                                                   const float* __restrict__ W_ih,
                                                   const float* __restrict__ W_hh,
                                                   float* __restrict__ W_eff,
                                                   float* __restrict__ biasp,
                                                   float* __restrict__ Wt) {
  int j = threadIdx.x;
  int n = blockIdx.x;
  float accw = 0.f, accb = 0.f;
#pragma unroll 8
  for (int f = 0; f < FF; ++f) {
    float wv = W_ih[(n * FF + f) * G4 + j];
    accw = fmaf(w_gat[f], wv, accw);
    accb = fmaf(b_gat[f], wv, accb);
  }
  W_eff[n * G4 + j] = accw;
  biasp[n * G4 + j] = accb;
  __half* Wt16 = (__half*)Wt;
  int g0 = (n * G4 + j) * 4;
#pragma unroll
  for (int qq = 0; qq < 4; ++qq) {
    int E = g0 + qq;
    int tl = E >> 7;             // lstm thread 0..511
    int idx = E & 127;
    int frag = idx >> 3;         // 0..15
    int e = idx & 7;
    int g = frag >> 2, q = frag & 3;
    int w = tl >> 6, l = tl & 63;
    int k = q * 32 + ((l >> 4) * 8) + e;
    int col = g * 128 + w * 16 + (l & 15);
    Wt16[E] = __float2half(W_hh[k * G4 + col]);
  }
}

// ---------------- fused GAT + xw: 32 positions per block (R20-verified) ----------------
__global__ __launch_bounds__(256) void gatxw_kernel(const float* __restrict__ x_seq,
                                                    const int* __restrict__ ei,
                                                    const float* __restrict__ w_gat,
                                                    const float* __restrict__ att_src,
                                                    const float* __restrict__ att_dst,
                                                    const float* __restrict__ b_ih,
                                                    const float* __restrict__ b_hh,
                                                    const float* __restrict__ W_eff,
                                                    const float* __restrict__ biasp,
                                                    float* __restrict__ xw) {
  __shared__ int srt[ET];
  __shared__ int offs[NN + 1];
  __shared__ int cnt[NN];
  __shared__ float xs[POSB * NN];   // 1024
  __shared__ float sl[POSB * NN];   // 1024
  __shared__ float scal_sh[2];
  int tid = threadIdx.x;
  int posbase = blockIdx.x * POSB;
  float we0[NN], we1[NN];
#pragma unroll
  for (int nn = 0; nn < NN; ++nn) {
    we0[nn] = W_eff[nn * G4 + tid];
    we1[nn] = W_eff[nn * G4 + 256 + tid];
  }
  float b0 = b_ih[tid] + b_hh[tid];
  float b1 = b_ih[256 + tid] + b_hh[256 + tid];
#pragma unroll 8
  for (int n = 0; n < NN; ++n) {
    b0 += biasp[n * G4 + tid];
    b1 += biasp[n * G4 + 256 + tid];
  }
  if (tid < NN) cnt[tid] = 0;
  __syncthreads();
  int es = 0, ed = 0, tk = 0;
  if (tid < ET) {
    if (tid < 96) { es = ei[tid]; ed = ei[96 + tid]; }
    else { es = tid - 96; ed = tid - 96; }
    tk = atomicAdd(&cnt[ed], 1);
  }
  __syncthreads();
  if (tid == 0) {
    offs[0] = 0;
    for (int n = 0; n < NN; ++n) offs[n + 1] = offs[n] + cnt[n];
  }
  if (tid == 1) {
    float cs = 0.f, cd = 0.f;
    for (int f = 0; f < FF; ++f) {
      cs = fmaf(w_gat[f], att_src[f], cs);
      cd = fmaf(w_gat[f], att_dst[f], cd);
    }
    scal_sh[0] = cs;
    scal_sh[1] = cd;
  }
  __syncthreads();
  if (tid < ET) srt[offs[ed] + tk] = es;
#pragma unroll
  for (int c = 0; c < POSB * NN / 256; ++c)
    xs[c * 256 + tid] = x_seq[posbase * NN + c * 256 + tid];  // coalesced
  __syncthreads();
  float cs = scal_sh[0], cd = scal_sh[1];
  int n = tid & 31;
  int e0 = offs[n], e1 = offs[n + 1];
#pragma unroll
  for (int pb = 0; pb < POSB / 8; ++pb) {
    int p = pb * 8 + (tid >> 5);
    int base = p * 32;
    float xn = xs[base + n];
    float cdxn = cd * xn;
    float m = -3.0e38f;
    for (int e = e0; e < e1; ++e) {
      float ev = fmaf(cs, xs[base + srt[e]], cdxn);
      ev = ev > 0.f ? ev : 0.2f * ev;  // LeakyReLU(0.2)
      m = fmaxf(m, ev);
    }
    float z = 0.f, sa = 0.f;
    for (int e = e0; e < e1; ++e) {
      float xsv = xs[base + srt[e]];
      float ev = fmaf(cs, xsv, cdxn);
      ev = ev > 0.f ? ev : 0.2f * ev;
      float ex = __expf(ev - m);
      z += ex;
      sa = fmaf(ex, xsv, sa);
    }
    sl[base + n] = sa * frcp(z);
  }
  __syncthreads();
#pragma unroll 4
  for (int pp = 0; pp < POSB; ++pp) {
    const float4* sp = (const float4*)&sl[pp * 32];
    float a0 = b0, a1 = b1;
#pragma unroll
    for (int q = 0; q < 8; ++q) {
      float4 sv = sp[q];
      a0 = fmaf(sv.x, we0[4 * q], a0);
      a0 = fmaf(sv.y, we0[4 * q + 1], a0);
      a0 = fmaf(sv.z, we0[4 * q + 2], a0);
      a0 = fmaf(sv.w, we0[4 * q + 3], a0);
      a1 = fmaf(sv.x, we1[4 * q], a1);
      a1 = fmaf(sv.y, we1[4 * q + 1], a1);
      a1 = fmaf(sv.z, we1[4 * q + 2], a1);
      a1 = fmaf(sv.w, we1[4 * q + 3], a1);
    }
    size_t row = (size_t)(posbase + pp) * G4;
    xw[row + tid] = a0;
    xw[row + 256 + tid] = a1;
  }
}

// ---------------- LSTM scan: R25 — MFMA GEMV, lane-local gates (VERIFIED 229.4us) ----------------
// Final map (R13-R27): step = issue(~350cy, 2 waves/SIMD mutually fill latency windows —
// R27 proved 1 wave/SIMD is WORSE) + ~725cy exposed latency/resync invariant to LDS traffic
// (R15/16), bank patterns (R16), TLP up (R17), ILP (R18), dataflow fusion (R26), wave count
// down (R27). MFMA reformulation: A = h broadcast to 16 rows; B tiles give wave w units
// w*16..+15 x 4 gates; C/D layout (col=lane&15) puts all 4 gate pre-acts for unit
// w*16+(l&15) in reg0 on EVERY lane -> no reduce, no gather, no divergence, c lane-local.
// xw folds into acc init (reg0 re-init each step; regs1-3 accumulate bounded row-sums,
// never read). 4-way redundant across l>>4 groups.
//
// Regs: v32-47 A frags | v64-127 B (16 frags x 4) | v194 xaddr | v195/196 rdA/B |
// v197/198 wrA/B | v199 c | v200 -log2e | v201 2log2e | v204-211 act temps |
// v216-231 acc (i,f,g,o) | v240-247 x ring (2 phases x 4 gates)

#define MFMA_Q(AQ, BI, BF, BG, BO) \
  "v_mfma_f32_16x16x32_f16 v[216:219], v[" AQ "], v[" BI "], v[216:219]\n\t" \
  "v_mfma_f32_16x16x32_f16 v[220:223], v[" AQ "], v[" BF "], v[220:223]\n\t" \
  "v_mfma_f32_16x16x32_f16 v[224:227], v[" AQ "], v[" BG "], v[224:227]\n\t" \
  "v_mfma_f32_16x16x32_f16 v[228:231], v[" AQ "], v[" BO "], v[228:231]\n\t"

#define PHASE(X0, X1, X2, X3, RD, WR) \
  "s_waitcnt vmcnt(4)\n\t" \
  "v_mov_b32 v216, " X0 "\n\t" \
  "v_mov_b32 v220, " X1 "\n\t" \
  "v_mov_b32 v224, " X2 "\n\t" \
  "v_mov_b32 v228, " X3 "\n\t" \
  "ds_read_b128 v[32:35], " RD "\n\t" \
  "ds_read_b128 v[36:39], " RD " offset:64\n\t" \
  "ds_read_b128 v[40:43], " RD " offset:128\n\t" \
  "ds_read_b128 v[44:47], " RD " offset:192\n\t" \
  "s_waitcnt lgkmcnt(3)\n\t" \
  MFMA_Q("32:35", "64:67",   "80:83",   "96:99",   "112:115") \
  "s_waitcnt lgkmcnt(2)\n\t" \
  MFMA_Q("36:39", "68:71",   "84:87",   "100:103", "116:119") \
  "s_waitcnt lgkmcnt(1)\n\t" \
  MFMA_Q("40:43", "72:75",   "88:91",   "104:107", "120:123") \
  "s_waitcnt lgkmcnt(0)\n\t" \
  MFMA_Q("44:47", "76:79",   "92:95",   "108:111", "124:127") \
  "global_load_dword " X0 ", v194, %[xwb]\n\t" \
  "global_load_dword " X1 ", v194, %[xwb] offset:512\n\t" \
  "global_load_dword " X2 ", v194, %[xwb] offset:1024\n\t" \
  "global_load_dword " X3 ", v194, %[xwb] offset:1536\n\t" \
  "v_add_u32 v194, 0x800, v194\n\t" \
  "s_nop 7\n\t" \
  "s_nop 7\n\t" \
  "v_mul_f32 v204, v200, v216\n\t" \
  "v_mul_f32 v205, v200, v220\n\t" \
  "v_mul_f32 v206, v201, v224\n\t" \
  "v_mul_f32 v207, v200, v228\n\t" \
  "v_exp_f32 v204, v204\n\t" \
  "v_exp_f32 v205, v205\n\t" \
  "v_exp_f32 v206, v206\n\t" \
  "v_exp_f32 v207, v207\n\t" \
  "v_add_f32 v204, 1.0, v204\n\t" \
  "v_add_f32 v205, 1.0, v205\n\t" \
  "v_add_f32 v206, 1.0, v206\n\t" \
  "v_add_f32 v207, 1.0, v207\n\t" \
  "v_rcp_f32 v204, v204\n\t" \
  "v_rcp_f32 v205, v205\n\t" \
  "v_rcp_f32 v206, v206\n\t" \
  "v_rcp_f32 v207, v207\n\t" \
  "v_fma_f32 v206, -2.0, v206, 1.0\n\t" \
  "v_mul_f32 v210, v204, v206\n\t" \
  "v_fma_f32 v199, v205, v199, v210\n\t" \
  "v_mul_f32 v211, v201, v199\n\t" \
  "v_exp_f32 v211, v211\n\t" \
  "s_nop 0\n\t" \
  "v_add_f32 v211, 1.0, v211\n\t" \
  "v_rcp_f32 v211, v211\n\t" \
  "s_nop 0\n\t" \
  "v_fma_f32 v211, -2.0, v211, 1.0\n\t" \
  "v_mul_f32 v211, v207, v211\n\t" \
  "v_cvt_f16_f32 v211, v211\n\t" \
  "ds_write_b16 " WR ", v211\n\t" \
  "s_waitcnt lgkmcnt(0)\n\t" \
  "s_barrier\n\t"

__global__ __launch_bounds__(512, 2) void lstm_kernel(const float* __restrict__ xw,
                                                      const float* __restrict__ Wt,
                                                      const float* __restrict__ W_fc,
                                                      const float* __restrict__ b_fc,
                                                      float* __restrict__ out) {
  __shared__ __align__(16) float hlds[128];  // f16 h: bufA bytes [0,256), bufB [256,512)
  int b = blockIdx.x, tid = threadIdx.x;
  int w = tid >> 6, l = tid & 63;
  int u = w * 16 + (l & 15);                 // hidden unit (4-way redundant over l>>4)
  if (tid < 128) hlds[tid] = 0.f;
  const float* xwb = xw + (size_t)b * TT * G4;
  unsigned xoff0 = (unsigned)(u * 4);        // xw f32, gate offsets via imm 512B
  unsigned wtoff = (unsigned)(tid * 256);    // 128 f16 = 256 B per thread
  unsigned lbase = (unsigned)(uintptr_t)&hlds[0];  // LDS aperture is 4GB-aligned
  unsigned rda = lbase + (unsigned)((l >> 4) * 16);  // A-frag k-chunk base
  unsigned rdb = rda + 256;
  unsigned wra = lbase + (unsigned)(u * 2);  // f16 element; 4-way same-addr write
  unsigned wrb = wra + 256;
  __syncthreads();
  asm volatile(
    "v_mov_b32 v194, %[xo]\n\t"
    "v_mov_b32 v195, %[rda]\n\t"
    "v_mov_b32 v196, %[rdb]\n\t"
    "v_mov_b32 v197, %[wra]\n\t"
    "v_mov_b32 v198, %[wrb]\n\t"
    "v_mov_b32 v199, 0\n\t"                   // c
    "v_mov_b32 v200, 0xbfb8aa3b\n\t"          // -log2e
    "v_mov_b32 v201, 0x4038aa3b\n\t"          // 2*log2e
    // zero acc regs 1-3 rows (never read; bounded growth) and reg0
    "v_mov_b32 v217, 0\n\t" "v_mov_b32 v218, 0\n\t" "v_mov_b32 v219, 0\n\t"
    "v_mov_b32 v221, 0\n\t" "v_mov_b32 v222, 0\n\t" "v_mov_b32 v223, 0\n\t"
    "v_mov_b32 v225, 0\n\t" "v_mov_b32 v226, 0\n\t" "v_mov_b32 v227, 0\n\t"
    "v_mov_b32 v229, 0\n\t" "v_mov_b32 v230, 0\n\t" "v_mov_b32 v231, 0\n\t"
    // x ring: t=0 -> v240-243, t=1 -> v244-247 (one dword per gate)
    "global_load_dword v240, v194, %[xwb]\n\t"
    "global_load_dword v241, v194, %[xwb] offset:512\n\t"
    "global_load_dword v242, v194, %[xwb] offset:1024\n\t"
    "global_load_dword v243, v194, %[xwb] offset:1536\n\t"
    "v_add_u32 v194, 0x800, v194\n\t"
    "global_load_dword v244, v194, %[xwb]\n\t"
    "global_load_dword v245, v194, %[xwb] offset:512\n\t"
    "global_load_dword v246, v194, %[xwb] offset:1024\n\t"
    "global_load_dword v247, v194, %[xwb] offset:1536\n\t"
    "v_add_u32 v194, 0x800, v194\n\t"
    // 128 f16 B-frag weights -> v64..v127 (16 x dwordx4)
    "global_load_dwordx4 v[64:67], %[wto], %[wtb] offset:0\n\t"
    "global_load_dwordx4 v[68:71], %[wto], %[wtb] offset:16\n\t"
    "global_load_dwordx4 v[72:75], %[wto], %[wtb] offset:32\n\t"
    "global_load_dwordx4 v[76:79], %[wto], %[wtb] offset:48\n\t"
    "global_load_dwordx4 v[80:83], %[wto], %[wtb] offset:64\n\t"
    "global_load_dwordx4 v[84:87], %[wto], %[wtb] offset:80\n\t"
    "global_load_dwordx4 v[88:91], %[wto], %[wtb] offset:96\n\t"
    "global_load_dwordx4 v[92:95], %[wto], %[wtb] offset:112\n\t"
    "global_load_dwordx4 v[96:99], %[wto], %[wtb] offset:128\n\t"
    "global_load_dwordx4 v[100:103], %[wto], %[wtb] offset:144\n\t"
    "global_load_dwordx4 v[104:107], %[wto], %[wtb] offset:160\n\t"
    "global_load_dwordx4 v[108:111], %[wto], %[wtb] offset:176\n\t"
    "global_load_dwordx4 v[112:115], %[wto], %[wtb] offset:192\n\t"
    "global_load_dwordx4 v[116:119], %[wto], %[wtb] offset:208\n\t"
    "global_load_dwordx4 v[120:123], %[wto], %[wtb] offset:224\n\t"
    "global_load_dwordx4 v[124:127], %[wto], %[wtb] offset:240\n\t"
    "s_waitcnt vmcnt(0)\n\t"
    "s_movk_i32 s20, 0x100\n\t"    // 256 iterations x 2 phases = 512 steps
    "L_lstm_%=:\n\t"
    PHASE("v240", "v241", "v242", "v243", "v195", "v198")   // t even: read A, write B
    PHASE("v244", "v245", "v246", "v247", "v196", "v197")   // t odd:  read B, write A
    "s_sub_u32 s20, s20, 1\n\t"
    "s_cmp_lg_u32 s20, 0\n\t"
    "s_cbranch_scc1 L_lstm_%=\n\t"
    "s_waitcnt vmcnt(0) lgkmcnt(0)\n\t"
    :
    : [xwb]"s"(xwb), [wtb]"s"(Wt), [wto]"v"(wtoff), [xo]"v"(xoff0),
      [rda]"v"(rda), [rdb]"v"(rdb), [wra]"v"(wra), [wrb]"v"(wrb)
    : "memory", "scc", "s20",
      "v32","v33","v34","v35","v36","v37","v38","v39",
      "v40","v41","v42","v43","v44","v45","v46","v47",
      "v64","v65","v66","v67","v68","v69","v70","v71",
      "v72","v73","v74","v75","v76","v77","v78","v79",
      "v80","v81","v82","v83","v84","v85","v86","v87",
      "v88","v89","v90","v91","v92","v93","v94","v95",
      "v96","v97","v98","v99","v100","v101","v102","v103",
      "v104","v105","v106","v107","v108","v109","v110","v111",
      "v112","v113","v114","v115","v116","v117","v118","v119",
      "v120","v121","v122","v123","v124","v125","v126","v127",
      "v194","v195","v196","v197","v198","v199","v200","v201",
      "v204","v205","v206","v207","v208","v209","v210","v211",
      "v216","v217","v218","v219","v220","v221","v222","v223",
      "v224","v225","v226","v227","v228","v229","v230","v231",
      "v240","v241","v242","v243","v244","v245","v246","v247");
  __syncthreads();
  // final h (after t=511, odd -> buffer A): f16 linear hlds bytes [0,256)
  if (tid < 4) {
    const __half* hf = (const __half*)hlds;
    float acc = b_fc[tid];
#pragma unroll 8
    for (int k = 0; k < HH; ++k)
      acc = fmaf(__half2float(hf[k]), W_fc[k * 4 + tid], acc);
    out[b * 4 + tid] = acc;
  }
}

extern "C" void kernel_launch(void* const* d_in, const int* in_sizes, int n_in,
                              void* d_out, int out_size, void* d_ws, size_t ws_size,
                              hipStream_t stream) {
  const float* x_seq   = (const float*)d_in[0];
  const int*   ei      = (const int*)d_in[1];
  const float* w_gat   = (const float*)d_in[2];
  const float* att_src = (const float*)d_in[3];
  const float* att_dst = (const float*)d_in[4];
  const float* b_gat   = (const float*)d_in[5];
  const float* W_ih    = (const float*)d_in[6];
  const float* W_hh    = (const float*)d_in[7];
  const float* b_ih    = (const float*)d_in[8];
  const float* b_hh    = (const float*)d_in[9];
  const float* W_fc    = (const float*)d_in[10];
  const float* b_fc    = (const float*)d_in[11];

  float* ws = (float*)d_ws;
  float* Wt    = ws;                            // 65536 f16 used (region reserved as 65536 f32)
  float* xw    = Wt + 65536;                    // (16384+8)*512 f (pad rows: 2-deep prefetch)
  float* W_eff = xw + (size_t)(NPOS + 8) * G4;  // 32*512
  float* biasp = W_eff + NN * G4;               // 32*512

  prep_kernel<<<NN, G4, 0, stream>>>(w_gat, b_gat, W_ih, W_hh, W_eff, biasp, Wt);
  gatxw_kernel<<<NPOS / POSB, 256, 0, stream>>>(x_seq, ei, w_gat, att_src, att_dst,
                                                b_ih, b_hh, W_eff, biasp, xw);
  lstm_kernel<<<BB, G4, 0, stream>>>(xw, Wt, W_fc, b_fc, (float*)d_out);
}